// Round 7
// baseline (322.770 us; speedup 1.0000x reference)
//
#include <hip/hip_runtime.h>

// Hex conv:  y[h,w,f] = relu( bias[f] + sum_taps x[h+dr, w+dc, c] * K[kr,kc][c][f] )
// parity p = h&1:
//   p==0 (7 taps): (dr,dc,kr,kc) = (0,0,0,1)(0,1,0,2)(1,-1,1,0)(1,0,1,1)(1,1,1,2)(2,0,2,1)(2,1,2,2)
//   p==1 (4 taps): (0,-1,0,1)(0,0,0,2)(1,-1,2,1)(1,0,2,2)
// x: (16,128,128,128) fp32 NHWC; K: (3,3,128,256) fp32 HWIO; bias: (256,) fp32.
// out: (16,128,128,256) fp32.

#define N_  16
#define H_  128
#define W_  128
#define C_  128
#define F_  256

typedef short bf16x8 __attribute__((ext_vector_type(8)));  // 8 bf16 in 4 VGPRs
typedef float f32x4  __attribute__((ext_vector_type(4)));

__device__ __forceinline__ unsigned int bf_bits(float f) {
  unsigned int u = __float_as_uint(f);
  return (u + 0x7FFFu + ((u >> 16) & 1u)) >> 16;   // RNE fp32 -> bf16
}
__device__ __forceinline__ unsigned int pack2(float a, float b) {
  return bf_bits(a) | (bf_bits(b) << 16);
}

__device__ __forceinline__ void tap_info(int t, int& dr, int& dc, int& kr, int& kc) {
  switch (t) {
    case 0:  dr = 0; dc = 0;  kr = 0; kc = 1; break;
    case 1:  dr = 0; dc = 1;  kr = 0; kc = 2; break;
    case 2:  dr = 1; dc = -1; kr = 1; kc = 0; break;
    case 3:  dr = 1; dc = 0;  kr = 1; kc = 1; break;
    case 4:  dr = 1; dc = 1;  kr = 1; kc = 2; break;
    case 5:  dr = 2; dc = 0;  kr = 2; kc = 1; break;
    case 6:  dr = 2; dc = 1;  kr = 2; kc = 2; break;
    case 7:  dr = 0; dc = -1; kr = 0; kc = 1; break;
    case 8:  dr = 0; dc = 0;  kr = 0; kc = 2; break;
    case 9:  dr = 1; dc = -1; kr = 2; kc = 1; break;
    default: dr = 1; dc = 0;  kr = 2; kc = 2; break;
  }
}

// ---------------- prep: packed transposed weights ----------------
// wt[t][f][c] (c contiguous, bf16 bits) = kernel[kr(t)][kc(t)][c][f]
__global__ __launch_bounds__(256) void build_w_kernel(
    const float* __restrict__ k, unsigned short* __restrict__ wt) {
  int tid = blockIdx.x * 256 + threadIdx.x;
  if (tid >= 11 * F_ * C_) return;
  int c = tid & 127;
  int f = (tid >> 7) & 255;
  int t = tid >> 15;
  int dr, dc, kr, kc;
  tap_info(t, dr, dc, kr, kc);
  float v = k[((kr * 3 + kc) * C_ + c) * F_ + f];
  wt[tid] = (unsigned short)bf_bits(v);
}

// ---------------- main conv: implicit GEMM, MFMA 16x16x32 bf16 ----------------
// block = 256 thr (4 waves, 2x2); tile = 128(w) x 128(f); per-wave 64x64; BK = 64
// LDS (double-buffered): A0 @0, A1 @16384; B0 @32768, B1 @49152 (16 KB each)
// Rows are 128B (64 bf16); 16B groups XOR-swizzled by (row&7) on write AND read.
// Schedule: one barrier per K-step; ds-writes of step s+1 overlap MFMA of s;
// global loads for s+2 issued during s.
__global__ __launch_bounds__(256, 2) void hconv_kernel(
    const float* __restrict__ x,
    const unsigned short* __restrict__ wt,
    const float* __restrict__ bias,
    float* __restrict__ out) {
  __shared__ __align__(16) char smem[65536];

  const int tid = threadIdx.x;
  // XCD-aware bijective swizzle: grid 4096 = 8 * 512
  const int bid = (blockIdx.x & 7) * 512 + (blockIdx.x >> 3);
  const int ft = bid & 1;
  const int h  = (bid >> 1) & 127;
  const int n  = bid >> 8;
  const int f0 = ft * 128;
  const int p  = h & 1;
  const int tap0   = p ? 7 : 0;
  const int nsteps = p ? 8 : 14;   // taps * (128/64)

  const int lane = tid & 63;
  const int wid  = tid >> 6;
  const int wr   = wid >> 1;       // w half (0..1)
  const int wc   = wid & 1;        // f half (0..1)
  const int l16  = lane & 15;
  const int lk   = lane >> 4;

  // staging map (both A and B): thread -> (row = tid>>1, 32-ch half = tid&1)
  const int srow  = tid >> 1;      // 0..127
  const int shalf = tid & 1;

  float4 ar[8];                    // 32 fp32 of x (one A row-half)
  uint4  br[4];                    // 32 bf16 of wt (one B row-half)

  auto load_step = [&](int s) {
    const int tap = tap0 + (s >> 1);
    const int cc  = s & 1;
    int dr, dc, kr, kc;
    tap_info(tap, dr, dc, kr, kc);
    const int hh = h + dr;
    const int wg = srow + dc;            // input column (BM == W)
    const bool av = (hh < H_) && (wg >= 0) && (wg < W_);
    if (av) {
      const float* ap = x + (((long)(n * H_ + hh) * W_ + wg) * C_ + cc * 64 + shalf * 32);
#pragma unroll
      for (int j = 0; j < 8; ++j) ar[j] = *(const float4*)(ap + j * 4);
    } else {
#pragma unroll
      for (int j = 0; j < 8; ++j) ar[j] = make_float4(0.f, 0.f, 0.f, 0.f);
    }
    const unsigned short* bp =
        wt + ((size_t)(tap * F_ + f0 + srow) * C_ + cc * 64 + shalf * 32);
    const uint4* bq = (const uint4*)bp;
#pragma unroll
    for (int j = 0; j < 4; ++j) br[j] = bq[j];
  };

  auto write_step = [&](int sel) {
    char* abase = (char*)smem + sel * 16384 + srow * 128;
    char* bbase = (char*)smem + 32768 + sel * 16384 + srow * 128;
    const int sw = srow & 7;
#pragma unroll
    for (int j = 0; j < 4; ++j) {
      uint4 u;
      u.x = pack2(ar[2 * j].x, ar[2 * j].y);
      u.y = pack2(ar[2 * j].z, ar[2 * j].w);
      u.z = pack2(ar[2 * j + 1].x, ar[2 * j + 1].y);
      u.w = pack2(ar[2 * j + 1].z, ar[2 * j + 1].w);
      *(uint4*)(abase + (((shalf * 4 + j) ^ sw) * 16)) = u;
    }
#pragma unroll
    for (int j = 0; j < 4; ++j)
      *(uint4*)(bbase + (((shalf * 4 + j) ^ sw) * 16)) = br[j];
  };

  f32x4 acc[4][4] = {};

  // Pipeline prologue: r(0) -> buf0, r(1) in regs
  load_step(0);
  write_step(0);
  load_step(1);
  __syncthreads();

  for (int s = 0; s < nsteps; ++s) {
    const int cur = s & 1;
    const char* ab = (const char*)smem + cur * 16384;
    const char* bb = (const char*)smem + 32768 + cur * 16384;

    // fragment reads from current buffer (issued before ds-writes: in-order
    // lgkm completion lets the compiler wait on reads without draining writes)
    bf16x8 af[4][2], bfr[4][2];
#pragma unroll
    for (int m = 0; m < 4; ++m)
#pragma unroll
      for (int kkk = 0; kkk < 2; ++kkk) {
        const int wl = wr * 64 + m * 16 + l16;
        const int g  = (kkk * 4 + lk) ^ (wl & 7);
        af[m][kkk] = *(const bf16x8*)(ab + wl * 128 + g * 16);
      }
#pragma unroll
    for (int fi = 0; fi < 4; ++fi)
#pragma unroll
      for (int kkk = 0; kkk < 2; ++kkk) {
        const int fl = wc * 64 + fi * 16 + l16;
        const int g  = (kkk * 4 + lk) ^ (fl & 7);
        bfr[fi][kkk] = *(const bf16x8*)(bb + fl * 128 + g * 16);
      }

    // stage r(s+1) into the other buffer (overlaps MFMA below)
    if (s + 1 < nsteps) write_step(cur ^ 1);
    // refill regs with r(s+2)
    if (s + 2 < nsteps) load_step(s + 2);

#pragma unroll
    for (int m = 0; m < 4; ++m)
#pragma unroll
      for (int fi = 0; fi < 4; ++fi)
#pragma unroll
        for (int kkk = 0; kkk < 2; ++kkk)
          acc[m][fi] = __builtin_amdgcn_mfma_f32_16x16x32_bf16(
              af[m][kkk], bfr[fi][kkk], acc[m][fi], 0, 0, 0);

    __syncthreads();
  }

  // epilogue: + bias, relu, fp32 store.  D: col(f)=lane&15, row(w)=(lane>>4)*4+r
#pragma unroll
  for (int fi = 0; fi < 4; ++fi) {
    const int f = f0 + wc * 64 + fi * 16 + l16;
    const float bv = bias[f];
#pragma unroll
    for (int m = 0; m < 4; ++m) {
      const int w = wr * 64 + m * 16 + lk * 4;
      float* o = out + (((size_t)(n * H_ + h) * W_ + w) * F_ + f);
#pragma unroll
      for (int r = 0; r < 4; ++r) {
        float v = acc[m][fi][r] + bv;
        v = v > 0.f ? v : 0.f;
        o[(size_t)r * F_] = v;
      }
    }
  }
}

extern "C" void kernel_launch(void* const* d_in, const int* in_sizes, int n_in,
                              void* d_out, int out_size, void* d_ws, size_t ws_size,
                              hipStream_t stream) {
  const float* x    = (const float*)d_in[0];
  const float* kern = (const float*)d_in[1];
  const float* bias = (const float*)d_in[2];
  float* out = (float*)d_out;
  unsigned short* wt = (unsigned short*)d_ws;   // 11*256*128*2 = 720,896 bytes

  {
    int total = 11 * F_ * C_;   // 360448
    build_w_kernel<<<(total + 255) / 256, 256, 0, stream>>>(kern, wt);
  }
  {
    int blocks = N_ * H_ * 2;   // 4096: (n, h, f-tile)
    hconv_kernel<<<blocks, 256, 0, stream>>>(x, wt, bias, out);
  }
}